// Round 5
// baseline (97.168 us; speedup 1.0000x reference)
//
#include <hip/hip_runtime.h>

typedef short bf16x8 __attribute__((ext_vector_type(8)));
typedef float f32x16 __attribute__((ext_vector_type(16)));

#define BIG_F 1e10f
constexpr int B = 16;
constexpr int N = 4096;
constexpr int ROWS = 128;         // x-rows per chamfer block
constexpr int COLS = 512;         // y-cols per chamfer block
constexpr int NRB = N / ROWS;     // 32 row-blocks
constexpr int NCB = N / COLS;     // 8 col-blocks

// truncating bf16 hi/lo split: v ~= hi + lo
__device__ __forceinline__ void split(float v, unsigned& h, unsigned& l) {
    unsigned hb = __float_as_uint(v) & 0xFFFF0000u;
    h = hb >> 16;
    float r = v - __uint_as_float(hb);
    l = __float_as_uint(r) >> 16;
}

__device__ __forceinline__ float min3f(float a, float b, float c) {
    return fminf(fminf(a, b), c);   // fuses to v_min3_f32
}

__device__ __forceinline__ float vmin16(f32x16 C) {
    float u0 = min3f(C[0], C[1], C[2]);
    float u1 = min3f(C[3], C[4], C[5]);
    float u2 = min3f(C[6], C[7], C[8]);
    float u3 = min3f(C[9], C[10], C[11]);
    float u4 = min3f(C[12], C[13], C[14]);
    return min3f(min3f(u0, u1, u2), fminf(u3, u4), C[15]);
}

// MFMA layout (mfma_f32_32x32x16_bf16, all 16 K-slots used):
//   A_k(n) = [ah0..2, ah0..2, al0..2, al0..2, xxh, xxl, 1, 1]   (ah+al = -2x)
//   B_k(m) = [yh0..2, yl0..2, yh0..2, yl0..2, 1, 1, qh, ql]     (qh+ql = yy)
// pack_kernel packs each point ONCE into global uint4 fragments [b][khalf][pt]
// (R4 re-packed each y-point 32x and each x-point 8x inside chamfer blocks).
__global__ __launch_bounds__(256) void pack_kernel(
    const float* __restrict__ x, const float* __restrict__ y,
    const int* __restrict__ mask,
    uint4* __restrict__ Apg,   // [B][2][N]
    uint4* __restrict__ Bpg,   // [B][2][N]
    float* __restrict__ out)
{
    const int idx = blockIdx.x * 256 + threadIdx.x;   // 65536 = 16 * 4096
    if (idx == 0) out[0] = 0.0f;                      // finalize accumulates later
    const int b  = idx >> 12;
    const int pt = idx & (N - 1);
    const float* xb = x + (size_t)b * 3 * N;
    const float* yb = y + (size_t)b * 3 * N;
    const float madd = mask[b * N + pt] ? 0.0f : BIG_F;
    {   // x -> A fragments
        float x0 = xb[pt], x1 = xb[N + pt], x2 = xb[2 * N + pt];
        float xx = fmaf(x2, x2, fmaf(x1, x1, x0 * x0)) + madd;
        unsigned h0, l0, h1, l1, h2, l2, xh, xl;
        split(-2.0f * x0, h0, l0);
        split(-2.0f * x1, h1, l1);
        split(-2.0f * x2, h2, l2);
        split(xx, xh, xl);
        uint4 w0 = { h0 | (h1 << 16), h2 | (h0 << 16), h1 | (h2 << 16), l0 | (l1 << 16) };
        uint4 w1 = { l2 | (l0 << 16), l1 | (l2 << 16), xh | (xl << 16), 0x3F803F80u };
        Apg[(size_t)(b * 2 + 0) * N + pt] = w0;
        Apg[(size_t)(b * 2 + 1) * N + pt] = w1;
    }
    {   // y -> B fragments
        float y0 = yb[pt], y1 = yb[N + pt], y2 = yb[2 * N + pt];
        float yy = fmaf(y2, y2, fmaf(y1, y1, y0 * y0)) + madd;
        unsigned h0, l0, h1, l1, h2, l2, qh, ql;
        split(y0, h0, l0);
        split(y1, h1, l1);
        split(y2, h2, l2);
        split(yy, qh, ql);
        unsigned u0 = h0 | (h1 << 16);   // yh0 yh1
        unsigned u1 = h2 | (l0 << 16);   // yh2 yl0
        unsigned u2 = l1 | (l2 << 16);   // yl1 yl2
        uint4 w0 = { u0, u1, u2, u0 };
        uint4 w1 = { u1, u2, 0x3F803F80u, qh | (ql << 16) };
        Bpg[(size_t)(b * 2 + 0) * N + pt] = w0;
        Bpg[(size_t)(b * 2 + 1) * N + pt] = w1;
    }
}

// One-shot 128x512 block: copy-stage B (no VALU), A straight global->reg,
// 8 MFMA-pair iters, in-register/shfl min reductions.
// (256,4): 4 blocks/CU. unroll 1 keeps liveness ~100 regs (R3 lesson: full
// unroll hoists all B-fragments and spills at a 128-reg budget).
__global__ __launch_bounds__(256, 4) void chamfer_mfma(
    const uint4* __restrict__ Apg, const uint4* __restrict__ Bpg,
    float* __restrict__ rowpart,   // [B][NCB][N] row-min partials (over 512 cols)
    float* __restrict__ colpart)   // [B][NRB][N] col-min partials (over 128 rows)
{
    const int rb = blockIdx.x & 31;   // consecutive blocks share the y-slice (L2)
    const int cb = blockIdx.x >> 5;
    const int b  = blockIdx.y;
    const int t  = threadIdx.x;

    __shared__ __align__(16) unsigned short Bpack[2][COLS][8];   // 16 KB
    __shared__ float colbuf[4][COLS];                            // 8 KB

    // ---- stage B: 1024 uint4 fragments, 4 per thread, pure copy ----
    uint4* Bl = (uint4*)&Bpack[0][0][0];
    const uint4* Bg = Bpg + (size_t)b * 2 * N + cb * COLS;
#pragma unroll
    for (int k = 0; k < 4; ++k) {
        int i = t + k * 256;                      // i>>9 = khalf, i&511 = pos
        Bl[i] = Bg[(size_t)(i >> 9) * N + (i & 511)];
    }

    const int w    = t >> 6;    // wave 0..3, owns rows w*32..w*32+31
    const int L    = t & 63;
    const int half = L >> 5;    // k-half 0/1
    const int lc   = L & 31;    // row/col within 32-tile

    // ---- A fragment straight to regs (one 16B fragment per thread) ----
    uint4 av = Apg[(size_t)(b * 2 + half) * N + rb * ROWS + w * 32 + lc];
    bf16x8 afr = *(bf16x8*)&av;
    __syncthreads();            // drains staging stores too

    const unsigned short* Bb = &Bpack[half][lc][0];

    float rm[16];
#pragma unroll
    for (int r = 0; r < 16; ++r) rm[r] = 1e30f;

    const f32x16 z16 = {0.f,0.f,0.f,0.f,0.f,0.f,0.f,0.f,
                        0.f,0.f,0.f,0.f,0.f,0.f,0.f,0.f};

#pragma unroll 1
    for (int p = 0; p < 8; ++p) {          // 8 col-pairs of 32 = 512 cols
        bf16x8 bf0 = *(const bf16x8*)(Bb + p * 512);
        bf16x8 bf1 = *(const bf16x8*)(Bb + p * 512 + 256);
        f32x16 C0 = __builtin_amdgcn_mfma_f32_32x32x16_bf16(afr, bf0, z16, 0, 0, 0);
        f32x16 C1 = __builtin_amdgcn_mfma_f32_32x32x16_bf16(afr, bf1, z16, 0, 0, 0);
        // row-mins: C[r] is row w*32 + (r&3)+8*(r>>2)+4*half, col = p*64(+32)+lc
#pragma unroll
        for (int r = 0; r < 16; ++r) rm[r] = min3f(rm[r], C0[r], C1[r]);
        // col partial: min over this half's 16 rows, then cross-half via shfl
        float v0 = vmin16(C0), v1 = vmin16(C1);
        v0 = fminf(v0, __shfl_xor(v0, 32));
        v1 = fminf(v1, __shfl_xor(v1, 32));
        if (half == 0) {
            colbuf[w][p * 64 + lc]      = v0;   // min over wave's 32 rows
            colbuf[w][p * 64 + 32 + lc] = v1;
        }
    }

    // finish row-mins: reduce across the 32 col-lanes (stays within 32-lane half)
#pragma unroll
    for (int off = 1; off <= 16; off <<= 1)
#pragma unroll
        for (int r = 0; r < 16; ++r)
            rm[r] = fminf(rm[r], __shfl_xor(rm[r], off));
    if (lc == 0) {
        float* rp = rowpart + ((size_t)b * NCB + cb) * N + rb * ROWS + w * 32 + half * 4;
#pragma unroll
        for (int r = 0; r < 16; ++r)
            rp[(r & 3) + 8 * (r >> 2)] = rm[r];
    }

    __syncthreads();
    // combine 4 waves' col partials -> block col partial (min over 128 rows)
    float* cpo = colpart + ((size_t)b * NRB + rb) * N + cb * COLS;
#pragma unroll
    for (int i = 0; i < 2; ++i) {
        int c = t + i * 256;
        float v = fminf(fminf(colbuf[0][c], colbuf[1][c]),
                        fminf(colbuf[2][c], colbuf[3][c]));
        cpo[c] = v;
    }
}

__global__ __launch_bounds__(256) void finalize_kernel(
    const int* __restrict__ mask,
    const float* __restrict__ rowpart, const float* __restrict__ colpart,
    float* __restrict__ out)
{
    const int b = blockIdx.x & 15;
    const int q = blockIdx.x >> 4;   // quarter 0..3
    const int t = threadIdx.x;
    const int* mrow = mask + b * N;

    // full-batch valid count (L2-resident)
    int cnt = 0;
    for (int i = t; i < N / 4; i += 256) {
        int4 mk = ((const int4*)mrow)[i];
        cnt += mk.x + mk.y + mk.z + mk.w;
    }

    const int p0 = q * 1024 + t * 4;

    // min over the 32 col-partial slabs
    const float* cp = colpart + (size_t)b * NRB * N + p0;
    float4 mn = *(const float4*)cp;
#pragma unroll 4
    for (int pb = 1; pb < NRB; ++pb) {
        float4 v = *(const float4*)(cp + (size_t)pb * N);
        mn.x = fminf(mn.x, v.x); mn.y = fminf(mn.y, v.y);
        mn.z = fminf(mn.z, v.z); mn.w = fminf(mn.w, v.w);
    }
    // min over the 8 row-partial slabs
    const float* rp = rowpart + (size_t)b * NCB * N + p0;
    float4 rn = *(const float4*)rp;
#pragma unroll
    for (int pb = 1; pb < NCB; ++pb) {
        float4 v = *(const float4*)(rp + (size_t)pb * N);
        rn.x = fminf(rn.x, v.x); rn.y = fminf(rn.y, v.y);
        rn.z = fminf(rn.z, v.z); rn.w = fminf(rn.w, v.w);
    }
    int4 mk = *(const int4*)(mrow + p0);
    float s = (mk.x ? (mn.x + rn.x) : 0.f) + (mk.y ? (mn.y + rn.y) : 0.f)
            + (mk.z ? (mn.z + rn.z) : 0.f) + (mk.w ? (mn.w + rn.w) : 0.f);

    for (int off = 32; off > 0; off >>= 1) {
        s   += __shfl_down(s, off);
        cnt += __shfl_down(cnt, off);
    }
    __shared__ float rs[4];
    __shared__ int   rc[4];
    const int wv = t >> 6;
    if ((t & 63) == 0) { rs[wv] = s; rc[wv] = cnt; }
    __syncthreads();
    if (t == 0) {
        float S = rs[0] + rs[1] + rs[2] + rs[3];
        float C = (float)(rc[0] + rc[1] + rc[2] + rc[3]);
        atomicAdd(out, (S / C) * (1.0f / 16.0f));
    }
}

extern "C" void kernel_launch(void* const* d_in, const int* in_sizes, int n_in,
                              void* d_out, int out_size, void* d_ws, size_t ws_size,
                              hipStream_t stream) {
    const float* x    = (const float*)d_in[0];
    const float* y    = (const float*)d_in[1];
    const int*   mask = (const int*)d_in[2];

    uint4* Apg     = (uint4*)d_ws;                        // B*2*N uint4 = 2 MB
    uint4* Bpg     = Apg + (size_t)B * 2 * N;             // 2 MB
    float* rowpart = (float*)(Bpg + (size_t)B * 2 * N);   // B*NCB*N = 2 MB
    float* colpart = rowpart + (size_t)B * NCB * N;       // B*NRB*N = 8 MB

    pack_kernel<<<dim3(B * N / 256), 256, 0, stream>>>(
        x, y, mask, Apg, Bpg, (float*)d_out);
    chamfer_mfma<<<dim3(NRB * NCB, B), 256, 0, stream>>>(
        Apg, Bpg, rowpart, colpart);
    finalize_kernel<<<dim3(64), 256, 0, stream>>>(
        mask, rowpart, colpart, (float*)d_out);
}